// Round 8
// baseline (280.571 us; speedup 1.0000x reference)
//
#include <hip/hip_runtime.h>
#include <cfloat>

// ---------------------------------------------------------------------------
// VQ-VAE vector quantizer forward (MI355X / gfx950)
//   x        [32][64][64][64] f32   (B, D, H, W)
//   codebook [1024][64] f32
// out: x_q transposed back to [B,D,H,W] (8388608 f32)  +  loss scalar (1 f32)
//
// argmin_k ||x - c_k||^2  ==  argmax_k (x . c_k - ||c_k||^2/2)
// loss = 1.25 * mean(||x - c_idx||^2) ; SSE(pos) = ||x||^2 - 2*(score-1)
//
// R8 = R5 (proven 54 us) + three issue/latency fixes:
//  (1) acc C-init via ds_read_b128 of replicated hneg4 (f32x4) -> 0 movs/iter
//      (MFMA C operand is read-only; mh4 regs reused across all 4 pos-tiles)
//  (2) depth-2 B prefetch over tile PAIRS, fully unrolled (static slots)
//  (3) pair-merge best = max(max(best,pA),pB) -> v_max3_u32
// Register need ~118 -> __launch_bounds__(256,4) caps at 128 (no spill;
// R2/R6/R7 lesson: cap must exceed need, 1024-thr blocks get force-capped).
// ---------------------------------------------------------------------------

#define DD   64
#define HHWW 4096          // H*W
#define KC   1024
#define NBLK  2048         // one block per (b,h) row
#define NPOSD 8388608.0f   // N * D

typedef __bf16  bf16x8 __attribute__((ext_vector_type(8)));
typedef unsigned short u16x8 __attribute__((ext_vector_type(8)));
typedef float   f32x4  __attribute__((ext_vector_type(4)));

__device__ __forceinline__ unsigned short bf16_bits(float f) {
  unsigned u = __float_as_uint(f);
  return (unsigned short)((u + 0x7FFFu + ((u >> 16) & 1u)) >> 16);  // RNE
}

__device__ __forceinline__ unsigned int umax2(unsigned int a, unsigned int b) {
  return a > b ? a : b;
}

// global->LDS direct copy, 16B per lane. ldst wave-uniform; HW adds lane*16.
__device__ __forceinline__ void gload_lds16(const void* gsrc, void* ldst) {
  __builtin_amdgcn_global_load_lds(
      (const __attribute__((address_space(1))) unsigned int*)gsrc,
      (__attribute__((address_space(3))) unsigned int*)ldst, 16, 0, 0);
}

// --- precompute: fragment-ordered bf16 codebook + replicated (1-||c||^2/2) --
__global__ __launch_bounds__(256) void vq_pre(
    const float* __restrict__ cb,          // [1024][64]
    unsigned short* __restrict__ cb_frag,  // [tile=64][kk=2][lane=64][e=8]
    float* __restrict__ hneg4)             // [1024][4] : 1-||c||^2/2, x4
{
  int k = blockIdx.x * 256 + threadIdx.x;
  if (k >= KC) return;
  float c[DD];
  float sum = 0.f;
#pragma unroll
  for (int d = 0; d < DD; ++d) { c[d] = cb[k * DD + d]; sum += c[d] * c[d]; }
  const float m = 1.0f - 0.5f * sum;
  hneg4[k * 4 + 0] = m; hneg4[k * 4 + 1] = m;
  hneg4[k * 4 + 2] = m; hneg4[k * 4 + 3] = m;
  int t = k >> 4, l15 = k & 15;
#pragma unroll
  for (int kk = 0; kk < 2; ++kk)
#pragma unroll
    for (int g = 0; g < 4; ++g)
#pragma unroll
      for (int e = 0; e < 8; ++e)
        cb_frag[(((t * 2 + kk) * 64) + (g * 16 + l15)) * 8 + e] =
            bf16_bits(c[kk * 32 + g * 8 + e]);
}

// --- main: fused distance-GEMM + argmin + loss partial + output write ------
__global__ __launch_bounds__(256, 4) void vq_main(
    const float* __restrict__ x,
    const unsigned short* __restrict__ cb_frag,
    const float* __restrict__ hneg4,
    const float* __restrict__ cb,
    float* __restrict__ out,
    float* __restrict__ partials)
{
  __shared__ f32x4        mh4_lds[KC];    // 16 KB replicated C-init values
  __shared__ unsigned int cand[4][64];    //  1 KB per-wave winners
  __shared__ int          idx_lds[64];

  const int tid  = threadIdx.x;
  const int wv   = tid >> 6;
  const int lane = tid & 63;
  const int l15  = lane & 15;
  const int g    = lane >> 4;

  const int row = blockIdx.x;            // global (b,h) row, 0..2047
  const int b   = row >> 6;
  const int h   = row & 63;
  const float* xb = x + (size_t)b * DD * HHWW + h * 64;  // xb[d*4096 + w]

  // ---- stage hneg4 (16 KB) into LDS: 4 rounds of 16 B/thread ----
#pragma unroll
  for (int i = 0; i < 4; ++i)
    gload_lds16((const char*)hneg4 + i * 4096 + wv * 1024 + (size_t)lane * 16,
                (char*)mh4_lds + i * 4096 + wv * 1024);

  // ---- A fragments for the row's 64 positions (4 waves identical -> L1)
  //      + per-position ||x||^2. Layout matches B: i=lane&15, k=kk*32+g*8+e.
  bf16x8 afrag[4][2];
  float  xsq[4];
#pragma unroll
  for (int pt = 0; pt < 4; ++pt) {
    const int w = pt * 16 + l15;
    float s = 0.f;
#pragma unroll
    for (int kk = 0; kk < 2; ++kk) {
      const int dbase = kk * 32 + g * 8;
      u16x8 f;
#pragma unroll
      for (int e = 0; e < 8; ++e) {
        float v = xb[(size_t)(dbase + e) * HHWW + w];
        s += v * v;
        f[e] = bf16_bits(v);
      }
      afrag[pt][kk] = __builtin_bit_cast(bf16x8, f);
    }
    s += __shfl_xor(s, 16, 64);
    s += __shfl_xor(s, 32, 64);
    xsq[pt] = s;                         // full 64-dim ||x||^2, every lane
  }

  __syncthreads();                       // mh4_lds ready

  // ---- this wave's 16 code tiles (codes wv*256 .. +255), tile-pair loop ----
  // best = (score_bits & ~1023) | (1023-code); score ~[0.95,1.05] > 0 so
  // the bit pattern is order-preserving; ties prefer LOWER code (argmin).
  unsigned int best[4][4];
#pragma unroll
  for (int pt = 0; pt < 4; ++pt)
#pragma unroll
    for (int rr = 0; rr < 4; ++rr) best[pt][rr] = 0u;

  const unsigned int MASK = 0xFFFFFC00u;
  const int codec0 = 1023 - wv * 256 - l15;
  // cb_frag tile stride = 2048 B ([kk=2][lane=64][16B]); wave chunk = 16 tiles.
  const char*  bbase = (const char*)cb_frag + (size_t)wv * 16 * 2048 + (size_t)lane * 16;
  const f32x4* mhp   = mh4_lds + wv * 256 + l15;      // + t*16 per tile

  // prefetch slots: [0]=even tile, [1]=odd tile (depth-2: 4 loads in flight)
  bf16x8 pb0[2], pb1[2];
  f32x4  pmh[2];
  pb0[0] = *(const bf16x8*)(bbase);
  pb1[0] = *(const bf16x8*)(bbase + 1024);
  pb0[1] = *(const bf16x8*)(bbase + 2048);
  pb1[1] = *(const bf16x8*)(bbase + 3072);
  pmh[0] = mhp[0];
  pmh[1] = mhp[16];

#pragma unroll
  for (int t = 0; t < 16; t += 2) {
    const bf16x8 cA0 = pb0[0], cA1 = pb1[0];
    const bf16x8 cB0 = pb0[1], cB1 = pb1[1];
    const f32x4  mA  = pmh[0], mB  = pmh[1];

    // prefetch tiles t+2 / t+3 (tail clamps fold at compile time)
    const int tp = (t + 2 < 16) ? (t + 2) : t;
    const int tq = (t + 3 < 16) ? (t + 3) : (t + 1);
    pb0[0] = *(const bf16x8*)(bbase + tp * 2048);
    pb1[0] = *(const bf16x8*)(bbase + tp * 2048 + 1024);
    pb0[1] = *(const bf16x8*)(bbase + tq * 2048);
    pb1[1] = *(const bf16x8*)(bbase + tq * 2048 + 1024);
    pmh[0] = mhp[tp * 16];
    pmh[1] = mhp[tq * 16];

    const unsigned int codecA = (unsigned int)(codec0 - t * 16);
    const unsigned int codecB = (unsigned int)(codec0 - (t + 1) * 16);

#pragma unroll
    for (int pt = 0; pt < 4; ++pt) {
      f32x4 aA = __builtin_amdgcn_mfma_f32_16x16x32_bf16(afrag[pt][0], cA0, mA, 0, 0, 0);
      aA = __builtin_amdgcn_mfma_f32_16x16x32_bf16(afrag[pt][1], cA1, aA, 0, 0, 0);
      f32x4 aB = __builtin_amdgcn_mfma_f32_16x16x32_bf16(afrag[pt][0], cB0, mB, 0, 0, 0);
      aB = __builtin_amdgcn_mfma_f32_16x16x32_bf16(afrag[pt][1], cB1, aB, 0, 0, 0);
#pragma unroll
      for (int rr = 0; rr < 4; ++rr) {   // C/D: col=l15(code), row=g*4+rr(pos)
        const unsigned int pA_ = (__float_as_uint(aA[rr]) & MASK) | codecA;
        const unsigned int pB_ = (__float_as_uint(aB[rr]) & MASK) | codecB;
        best[pt][rr] = umax2(umax2(best[pt][rr], pA_), pB_);   // v_max3_u32
      }
    }
  }

  // ---- cross-lane max over the 16 code columns (l15) ----
#pragma unroll
  for (int pt = 0; pt < 4; ++pt)
#pragma unroll
    for (int rr = 0; rr < 4; ++rr) {
      unsigned int v = best[pt][rr];
#pragma unroll
      for (int m = 1; m < 16; m <<= 1) {
        unsigned int vo = __shfl_xor(v, m, 64);
        v = v > vo ? v : vo;
      }
      if (l15 == 0) cand[wv][pt * 16 + g * 4 + rr] = v;
    }

  __syncthreads();

  // ---- wave 0: merge the 4 K-split candidates, loss partial ----
  if (tid < 64) {
    unsigned int v01 = umax2(cand[0][tid], cand[1][tid]);
    unsigned int v23 = umax2(cand[2][tid], cand[3][tid]);
    unsigned int v   = umax2(v01, v23);
    idx_lds[tid] = 1023 - (int)(v & 1023u);
    const float vt = __uint_as_float(v & MASK);     // score + 1 (truncated)
    const int ptt = tid >> 4;                       // xsq[pt] select (static)
    float xq = xsq[0];
    if (ptt == 1) xq = xsq[1];
    if (ptt == 2) xq = xsq[2];
    if (ptt == 3) xq = xsq[3];
    float sse = __builtin_fmaf(vt, -2.0f, xq + 2.0f);
#pragma unroll
    for (int m = 1; m < 64; m <<= 1) sse += __shfl_xor(sse, m, 64);
    if (tid == 0) partials[blockIdx.x] = sse;
  }

  __syncthreads();

  // ---- write quantized output; float4 gather from row-major cb ----
  const int myidx = idx_lds[lane];       // position w = lane
  const float4* crow = (const float4*)(cb + (size_t)myidx * DD) + wv * 4;
  const float4 c0 = crow[0], c1 = crow[1], c2 = crow[2], c3 = crow[3];
  float* ob = out + (size_t)b * DD * HHWW + h * 64 + lane;
  ob[(size_t)(wv * 16 +  0) * HHWW] = c0.x;
  ob[(size_t)(wv * 16 +  1) * HHWW] = c0.y;
  ob[(size_t)(wv * 16 +  2) * HHWW] = c0.z;
  ob[(size_t)(wv * 16 +  3) * HHWW] = c0.w;
  ob[(size_t)(wv * 16 +  4) * HHWW] = c1.x;
  ob[(size_t)(wv * 16 +  5) * HHWW] = c1.y;
  ob[(size_t)(wv * 16 +  6) * HHWW] = c1.z;
  ob[(size_t)(wv * 16 +  7) * HHWW] = c1.w;
  ob[(size_t)(wv * 16 +  8) * HHWW] = c2.x;
  ob[(size_t)(wv * 16 +  9) * HHWW] = c2.y;
  ob[(size_t)(wv * 16 + 10) * HHWW] = c2.z;
  ob[(size_t)(wv * 16 + 11) * HHWW] = c2.w;
  ob[(size_t)(wv * 16 + 12) * HHWW] = c3.x;
  ob[(size_t)(wv * 16 + 13) * HHWW] = c3.y;
  ob[(size_t)(wv * 16 + 14) * HHWW] = c3.z;
  ob[(size_t)(wv * 16 + 15) * HHWW] = c3.w;
}

// --- final loss reduce ------------------------------------------------------
__global__ __launch_bounds__(256) void vq_loss(
    const float* __restrict__ partials, float* __restrict__ loss_out)
{
  __shared__ float sred[4];
  int tid = threadIdx.x;
  float s = 0.f;
  for (int i = tid; i < NBLK; i += 256) s += partials[i];
#pragma unroll
  for (int m = 1; m < 64; m <<= 1) s += __shfl_xor(s, m, 64);
  if ((tid & 63) == 0) sred[tid >> 6] = s;
  __syncthreads();
  if (tid == 0)
    loss_out[0] = (sred[0] + sred[1] + sred[2] + sred[3]) * (1.25f / NPOSD);
}

extern "C" void kernel_launch(void* const* d_in, const int* in_sizes, int n_in,
                              void* d_out, int out_size, void* d_ws, size_t ws_size,
                              hipStream_t stream) {
  const float* x  = (const float*)d_in[0];
  const float* cb = (const float*)d_in[1];
  float* out      = (float*)d_out;
  float* loss_out = out + 8388608;

  char* ws = (char*)d_ws;
  unsigned short* cb_frag = (unsigned short*)(ws);      // 131072 B
  float* hneg4    = (float*)(ws + 131072);              //  16384 B
  float* partials = (float*)(ws + 147456);              //   8192 B

  vq_pre <<<4,    256, 0, stream>>>(cb, cb_frag, hneg4);
  vq_main<<<NBLK, 256, 0, stream>>>(x, cb_frag, hneg4, cb, out, partials);
  vq_loss<<<1,    256, 0, stream>>>(partials, loss_out);
}

// Round 9
// 45.019 us; speedup vs baseline: 6.2323x; 6.2323x over previous
//
#include <hip/hip_runtime.h>
#include <cfloat>

// ---------------------------------------------------------------------------
// VQ-VAE vector quantizer forward (MI355X / gfx950)
//   x        [32][64][64][64] f32   (B, D, H, W)
//   codebook [1024][64] f32
// out: x_q transposed back to [B,D,H,W] (8388608 f32)  +  loss scalar (1 f32)
//
// argmin_k ||x - c_k||^2  ==  argmax_k (x . c_k - ||c_k||^2/2)
// Sum_p SSE_p = Sum x^2 - 2 * Sum_p (best_score_p - 1),
//   score = dot + 1 - ||c||^2/2 (C-init), packed-u32 argmax (R5-proven).
//
// R9 = R5 skeleton (block=row, 4 waves K-split, depth-1 L2 B-prefetch,
// 3 barriers, NO launch_bounds occupancy hint -- R2/R6/R7/R8 all spilled
// from hinted VGPR caps) + three targeted fixes:
//  (1) cooperative COALESCED x-staging (float4) -> bf16 fragment layout in
//      LDS; waves read A via 8x ds_read_b128 (kills 64 strided loads x4)
//  (2) mov-free C-init: acc = mfma(a,b, mh4) with mh4 ds_read_b128 from a
//      x4-replicated hneg table in LDS (kills 16 v_mov per iteration)
//  (3) loss via Sum x^2 (staging) - 2*Sum(vt-1) (merge) -> xsq regs deleted
// ---------------------------------------------------------------------------

#define DD   64
#define HHWW 4096          // H*W
#define KC   1024
#define NBLK  2048         // one block per (b,h) row
#define NPOSD 8388608.0f   // N * D

typedef __bf16  bf16x8 __attribute__((ext_vector_type(8)));
typedef float   f32x4  __attribute__((ext_vector_type(4)));

__device__ __forceinline__ unsigned short bf16_bits(float f) {
  unsigned u = __float_as_uint(f);
  return (unsigned short)((u + 0x7FFFu + ((u >> 16) & 1u)) >> 16);  // RNE
}

__device__ __forceinline__ unsigned int umax2(unsigned int a, unsigned int b) {
  return a > b ? a : b;
}

// global->LDS direct copy, 16B per lane. ldst wave-uniform; HW adds lane*16.
__device__ __forceinline__ void gload_lds16(const void* gsrc, void* ldst) {
  __builtin_amdgcn_global_load_lds(
      (const __attribute__((address_space(1))) unsigned int*)gsrc,
      (__attribute__((address_space(3))) unsigned int*)ldst, 16, 0, 0);
}

// --- precompute: fragment-ordered bf16 codebook + replicated (1-||c||^2/2) --
__global__ __launch_bounds__(256) void vq_pre(
    const float* __restrict__ cb,          // [1024][64]
    unsigned short* __restrict__ cb_frag,  // [tile=64][kk=2][lane=64][e=8]
    float* __restrict__ hneg4)             // [1024][4] : 1-||c||^2/2, x4
{
  int k = blockIdx.x * 256 + threadIdx.x;
  if (k >= KC) return;
  float c[DD];
  float sum = 0.f;
#pragma unroll
  for (int d = 0; d < DD; ++d) { c[d] = cb[k * DD + d]; sum += c[d] * c[d]; }
  const float m = 1.0f - 0.5f * sum;
  hneg4[k * 4 + 0] = m; hneg4[k * 4 + 1] = m;
  hneg4[k * 4 + 2] = m; hneg4[k * 4 + 3] = m;
  int t = k >> 4, l15 = k & 15;
#pragma unroll
  for (int kk = 0; kk < 2; ++kk)
#pragma unroll
    for (int g = 0; g < 4; ++g)
#pragma unroll
      for (int e = 0; e < 8; ++e)
        cb_frag[(((t * 2 + kk) * 64) + (g * 16 + l15)) * 8 + e] =
            bf16_bits(c[kk * 32 + g * 8 + e]);
}

// --- main: fused distance-GEMM + argmin + loss partial + output write ------
__global__ __launch_bounds__(256) void vq_main(
    const float* __restrict__ x,
    const unsigned short* __restrict__ cb_frag,
    const float* __restrict__ hneg4,
    const float* __restrict__ cb,
    float* __restrict__ out,
    float* __restrict__ partials)
{
  __shared__ unsigned short xfrag[4096];   //  8 KB: row A-fragments (bf16)
  __shared__ f32x4          mh4_lds[KC];   // 16 KB: replicated C-init values
  __shared__ unsigned int   cand[4][64];   //  1 KB: per-wave winners
  __shared__ int            idx_lds[64];
  __shared__ float          xred[4];

  const int tid  = threadIdx.x;
  const int wv   = tid >> 6;
  const int lane = tid & 63;
  const int l15  = lane & 15;

  const int row = blockIdx.x;            // global (b,h) row, 0..2047
  const int b   = row >> 6;
  const int h   = row & 63;
  const float* xb = x + (size_t)b * DD * HHWW + h * 64;  // xb[d*4096 + w]

  // ---- stage hneg4 (16 KB) into LDS: 4 async rounds of 16 B/thread ----
#pragma unroll
  for (int i = 0; i < 4; ++i)
    gload_lds16((const char*)hneg4 + i * 4096 + (size_t)tid * 16,
                (char*)mh4_lds + i * 4096 + wv * 1024);

  // ---- cooperative coalesced x-stage -> bf16 fragment layout in LDS ----
  // float4 #m covers (d = m>>4, w = (m&15)*4 .. +3); lanes contiguous ->
  // 256B segments. Pack to bf16; accumulate Sum x^2.
  float xacc = 0.f;
#pragma unroll
  for (int r4 = 0; r4 < 4; ++r4) {
    const int m  = tid + r4 * 256;
    const int d  = m >> 4;
    const int w4 = m & 15;
    const float4 v4 = *(const float4*)(xb + (size_t)d * HHWW + w4 * 4);
    const int kk = d >> 5, gg = (d >> 3) & 3, e = d & 7;
    const int pt = w4 >> 2;
    const int base = pt * 1024 + kk * 512 + gg * 128 + e;  // + l15*8
    const int lb = (w4 & 3) * 4;                           // l15 = lb + i
    xacc += v4.x * v4.x + v4.y * v4.y + v4.z * v4.z + v4.w * v4.w;
    xfrag[base + (lb + 0) * 8] = bf16_bits(v4.x);
    xfrag[base + (lb + 1) * 8] = bf16_bits(v4.y);
    xfrag[base + (lb + 2) * 8] = bf16_bits(v4.z);
    xfrag[base + (lb + 3) * 8] = bf16_bits(v4.w);
  }

  __syncthreads();                       // xfrag + mh4_lds ready

  // ---- A fragments from LDS (conflict-free ds_read_b128) ----
  // layout matches B: row i = lane&15, k = kk*32 + (lane>>4)*8 + e.
  bf16x8 afrag[4][2];
#pragma unroll
  for (int pt = 0; pt < 4; ++pt) {
    afrag[pt][0] = *(const bf16x8*)(&xfrag[pt * 1024 + lane * 8]);
    afrag[pt][1] = *(const bf16x8*)(&xfrag[pt * 1024 + 512 + lane * 8]);
  }

  // ---- this wave's 16 code tiles (codes wv*256 .. +255), depth-1 pf ----
  // best = (score_bits & ~1023) | (1023-code); score ~[0.95,1.05] > 0 so
  // bit pattern is order-preserving; ties prefer LOWER code (argmin).
  unsigned int best[4][4];
#pragma unroll
  for (int pt = 0; pt < 4; ++pt)
#pragma unroll
    for (int rr = 0; rr < 4; ++rr) best[pt][rr] = 0u;

  const unsigned int MASK = 0xFFFFFC00u;
  const int codec0 = 1023 - wv * 256 - l15;
  // cb_frag tile stride = 2048 B ([kk=2][lane=64][16B]); wave chunk = 16.
  const char*  bb  = (const char*)cb_frag + (size_t)wv * 16 * 2048 + (size_t)lane * 16;
  const f32x4* mhp = mh4_lds + wv * 256 + l15;   // + t*16 per tile

  bf16x8 nb0 = *(const bf16x8*)(bb);          // depth-1 prefetch (kk=0)
  bf16x8 nb1 = *(const bf16x8*)(bb + 1024);   // kk=1
  f32x4  nmh = mhp[0];

#pragma unroll 4
  for (int t = 0; t < 16; ++t) {
    const bf16x8 b0 = nb0, b1 = nb1;
    const f32x4  mh = nmh;
    const char* bn = bb + (size_t)(((t + 1) & 15) * 2048);
    nb0 = *(const bf16x8*)(bn);
    nb1 = *(const bf16x8*)(bn + 1024);
    nmh = mhp[((t + 1) & 15) * 16];

    const unsigned int codec = (unsigned int)(codec0 - t * 16);

    f32x4 acc[4];
#pragma unroll
    for (int pt = 0; pt < 4; ++pt)      // C-init = mh4 (no movs)
      acc[pt] = __builtin_amdgcn_mfma_f32_16x16x32_bf16(afrag[pt][0], b0, mh, 0, 0, 0);
#pragma unroll
    for (int pt = 0; pt < 4; ++pt)
      acc[pt] = __builtin_amdgcn_mfma_f32_16x16x32_bf16(afrag[pt][1], b1, acc[pt], 0, 0, 0);

#pragma unroll
    for (int pt = 0; pt < 4; ++pt)
#pragma unroll
      for (int rr = 0; rr < 4; ++rr) {  // C/D: col=l15(code), row=g*4+rr(pos)
        const unsigned int p = (__float_as_uint(acc[pt][rr]) & MASK) | codec;
        best[pt][rr] = umax2(best[pt][rr], p);   // v_and_or + v_max
      }
  }

  // ---- cross-lane max over the 16 code columns (l15) ----
  const int g = lane >> 4;
#pragma unroll
  for (int pt = 0; pt < 4; ++pt)
#pragma unroll
    for (int rr = 0; rr < 4; ++rr) {
      unsigned int v = best[pt][rr];
#pragma unroll
      for (int m = 1; m < 16; m <<= 1) {
        unsigned int vo = __shfl_xor(v, m, 64);
        v = umax2(v, vo);
      }
      if (l15 == 0) cand[wv][pt * 16 + g * 4 + rr] = v;
    }

  // per-wave Sum x^2 reduce
#pragma unroll
  for (int m = 1; m < 64; m <<= 1) xacc += __shfl_xor(xacc, m, 64);
  if (lane == 0) xred[wv] = xacc;

  __syncthreads();

  // ---- wave 0: merge the 4 K-split candidates; loss partial ----
  if (tid < 64) {
    unsigned int v01 = umax2(cand[0][tid], cand[1][tid]);
    unsigned int v23 = umax2(cand[2][tid], cand[3][tid]);
    unsigned int v   = umax2(v01, v23);
    idx_lds[tid] = 1023 - (int)(v & 1023u);
    float vt1 = __uint_as_float(v & MASK) - 1.0f;   // dot - csq/2 (trunc)
#pragma unroll
    for (int m = 1; m < 64; m <<= 1) vt1 += __shfl_xor(vt1, m, 64);
    if (tid == 0)
      partials[blockIdx.x] =
          (xred[0] + xred[1] + xred[2] + xred[3]) - 2.0f * vt1;
  }

  __syncthreads();

  // ---- write quantized output; float4 gather from row-major cb ----
  const int myidx = idx_lds[lane];       // position w = lane
  const float4* crow = (const float4*)(cb + (size_t)myidx * DD) + wv * 4;
  const float4 c0 = crow[0], c1 = crow[1], c2 = crow[2], c3 = crow[3];
  float* ob = out + (size_t)b * DD * HHWW + h * 64 + lane;
  ob[(size_t)(wv * 16 +  0) * HHWW] = c0.x;
  ob[(size_t)(wv * 16 +  1) * HHWW] = c0.y;
  ob[(size_t)(wv * 16 +  2) * HHWW] = c0.z;
  ob[(size_t)(wv * 16 +  3) * HHWW] = c0.w;
  ob[(size_t)(wv * 16 +  4) * HHWW] = c1.x;
  ob[(size_t)(wv * 16 +  5) * HHWW] = c1.y;
  ob[(size_t)(wv * 16 +  6) * HHWW] = c1.z;
  ob[(size_t)(wv * 16 +  7) * HHWW] = c1.w;
  ob[(size_t)(wv * 16 +  8) * HHWW] = c2.x;
  ob[(size_t)(wv * 16 +  9) * HHWW] = c2.y;
  ob[(size_t)(wv * 16 + 10) * HHWW] = c2.z;
  ob[(size_t)(wv * 16 + 11) * HHWW] = c2.w;
  ob[(size_t)(wv * 16 + 12) * HHWW] = c3.x;
  ob[(size_t)(wv * 16 + 13) * HHWW] = c3.y;
  ob[(size_t)(wv * 16 + 14) * HHWW] = c3.z;
  ob[(size_t)(wv * 16 + 15) * HHWW] = c3.w;
}

// --- final loss reduce ------------------------------------------------------
__global__ __launch_bounds__(256) void vq_loss(
    const float* __restrict__ partials, float* __restrict__ loss_out)
{
  __shared__ float sred[4];
  int tid = threadIdx.x;
  float s = 0.f;
  for (int i = tid; i < NBLK; i += 256) s += partials[i];
#pragma unroll
  for (int m = 1; m < 64; m <<= 1) s += __shfl_xor(s, m, 64);
  if ((tid & 63) == 0) sred[tid >> 6] = s;
  __syncthreads();
  if (tid == 0)
    loss_out[0] = (sred[0] + sred[1] + sred[2] + sred[3]) * (1.25f / NPOSD);
}

extern "C" void kernel_launch(void* const* d_in, const int* in_sizes, int n_in,
                              void* d_out, int out_size, void* d_ws, size_t ws_size,
                              hipStream_t stream) {
  const float* x  = (const float*)d_in[0];
  const float* cb = (const float*)d_in[1];
  float* out      = (float*)d_out;
  float* loss_out = out + 8388608;

  char* ws = (char*)d_ws;
  unsigned short* cb_frag = (unsigned short*)(ws);      // 131072 B
  float* hneg4    = (float*)(ws + 131072);              //  16384 B
  float* partials = (float*)(ws + 147456);              //   8192 B

  vq_pre <<<4,    256, 0, stream>>>(cb, cb_frag, hneg4);
  vq_main<<<NBLK, 256, 0, stream>>>(x, cb_frag, hneg4, cb, out, partials);
  vq_loss<<<1,    256, 0, stream>>>(partials, loss_out);
}